// Round 9
// baseline (206.872 us; speedup 1.0000x reference)
//
#include <hip/hip_runtime.h>
#include <math.h>

#define CB 8
#define CNX 512
#define CNR 512
#define CD 256
#define CH 256

__device__ __forceinline__ float fast_rcp(float x) {
#if __has_builtin(__builtin_amdgcn_rcpf)
  return __builtin_amdgcn_rcpf(x);
#else
  return 1.0f / x;
#endif
}
__device__ __forceinline__ float fast_exp2(float x) {
#if __has_builtin(__builtin_amdgcn_exp2f)
  return __builtin_amdgcn_exp2f(x);
#else
  return exp2f(x);
#endif
}

// Fused projections.
// z=0: exT[b][h][x] = exp(2*(X@W_X^T+b_X))  (transposed, x contiguous)
// z=1: erN[b][r][h] = exp(2*(ref@W_ref^T+b_ref)) (natural, h contiguous)
// 32(m) x 64(h) tile, K-tile 32, grid (128,4,2) = 1024 blocks (4/CU), block 256
// microtile: tx->m (2), ty->h (4); register-prefetch staging.
__global__ __launch_bounds__(256) void proj_fused(
    const float* __restrict__ A0, const float* __restrict__ A1,
    const float* __restrict__ W0, const float* __restrict__ W1,
    const float* __restrict__ bias0, const float* __restrict__ bias1,
    float* __restrict__ E0, float* __restrict__ E1) {
  __shared__ float As[32][33];  // [k][m]
  __shared__ float Ws[32][68];  // [k][h]
  const int K = CD;
  int z = blockIdx.z;
  const float* A = z ? A1 : A0;
  const float* W = z ? W1 : W0;
  const float* bias = z ? bias1 : bias0;
  int m0 = blockIdx.x * 32, n0 = blockIdx.y * 64;
  int tid = threadIdx.x;
  int tx = tid & 15, ty = tid >> 4;   // tx -> m(2), ty -> h(4)
  int arow = tid >> 3, ak4 = tid & 7; // A: 32 rows x 32 k
  float acc[2][4] = {};
  const float* pA = A + (size_t)(m0 + arow) * K + ak4 * 4;
  const float* pW0 = W + (size_t)(n0 + arow) * K + ak4 * 4;
  const float* pW1 = W + (size_t)(n0 + arow + 32) * K + ak4 * 4;
  float4 av = *(const float4*)(pA);
  float4 wv0 = *(const float4*)(pW0);
  float4 wv1 = *(const float4*)(pW1);
  for (int kt = 0; kt < K; kt += 32) {
    if (kt) __syncthreads();
    As[ak4 * 4 + 0][arow] = av.x;
    As[ak4 * 4 + 1][arow] = av.y;
    As[ak4 * 4 + 2][arow] = av.z;
    As[ak4 * 4 + 3][arow] = av.w;
    Ws[ak4 * 4 + 0][arow] = wv0.x;
    Ws[ak4 * 4 + 1][arow] = wv0.y;
    Ws[ak4 * 4 + 2][arow] = wv0.z;
    Ws[ak4 * 4 + 3][arow] = wv0.w;
    Ws[ak4 * 4 + 0][arow + 32] = wv1.x;
    Ws[ak4 * 4 + 1][arow + 32] = wv1.y;
    Ws[ak4 * 4 + 2][arow + 32] = wv1.z;
    Ws[ak4 * 4 + 3][arow + 32] = wv1.w;
    __syncthreads();
    if (kt + 32 < K) {
      av = *(const float4*)(pA + kt + 32);
      wv0 = *(const float4*)(pW0 + kt + 32);
      wv1 = *(const float4*)(pW1 + kt + 32);
    }
#pragma unroll 8
    for (int k = 0; k < 32; k++) {
      float a0 = As[k][tx * 2], a1 = As[k][tx * 2 + 1];
      float4 w4 = *(const float4*)&Ws[k][ty * 4];
      float wm[4] = {w4.x, w4.y, w4.z, w4.w};
#pragma unroll
      for (int j = 0; j < 4; j++) {
        acc[0][j] = fmaf(a0, wm[j], acc[0][j]);
        acc[1][j] = fmaf(a1, wm[j], acc[1][j]);
      }
    }
  }
  const float K2L = 2.8853900817779268f;  // 2*log2(e)
  float4 bv = *(const float4*)(bias + n0 + ty * 4);
  float bm[4] = {bv.x, bv.y, bv.z, bv.w};
  if (z == 0) {
    int b = m0 >> 9;
    int xbase = (m0 & 511) + tx * 2;
#pragma unroll
    for (int j = 0; j < 4; j++) {
      int h = n0 + ty * 4 + j;
      float2 o = {fast_exp2(K2L * (acc[0][j] + bm[j])),
                  fast_exp2(K2L * (acc[1][j] + bm[j]))};
      *(float2*)(E0 + ((size_t)b * CH + h) * CNX + xbase) = o;
    }
  } else {
#pragma unroll
    for (int i = 0; i < 2; i++) {
      int m = m0 + tx * 2 + i;
      float4 o = {fast_exp2(K2L * (acc[i][0] + bm[0])),
                  fast_exp2(K2L * (acc[i][1] + bm[1])),
                  fast_exp2(K2L * (acc[i][2] + bm[2])),
                  fast_exp2(K2L * (acc[i][3] + bm[3]))};
      *(float4*)(E1 + (size_t)m * CH + n0 + ty * 4) = o;
    }
  }
}

// eT[b][r][x] = exp(-2 * sum_h v_w[h] / (exT[b][h][x]*erN[b][r][h] + 1))
// No LDS/barriers. Lanes carry x (coalesced ex); r,h wave-uniform -> er,v_w
// scalarize to SGPR loads. Explicit one-hq-ahead double buffer on all streams.
// grid (NX/64=8, NR/16=32, B=8) = 2048 blocks (8/CU), 4 waves, 4 r/wave.
__global__ __launch_bounds__(256) void scores_kernel(
    const float* __restrict__ exT, const float* __restrict__ erN,
    const float* __restrict__ v_w, float* __restrict__ eT) {
  int b = blockIdx.z;
  int tid = threadIdx.x;
  int lane = tid & 63;
  int wv = __builtin_amdgcn_readfirstlane(tid >> 6);
  int x = blockIdx.x * 64 + lane;
  int r0 = blockIdx.y * 16 + wv * 4;
  const float* pX = exT + (size_t)b * CH * CNX + x;
  const float* pR = erN + ((size_t)b * CNR + r0) * CH;
  float acc[4] = {};
  float exn[4];
  float4 ern[4];
  float4 vvn;
#pragma unroll
  for (int k = 0; k < 4; k++) exn[k] = pX[(size_t)k * CNX];
#pragma unroll
  for (int r = 0; r < 4; r++) ern[r] = *(const float4*)(pR + (size_t)r * CH);
  vvn = *(const float4*)(v_w);
#pragma unroll 2
  for (int hq = 0; hq < 64; hq++) {
    float exc[4];
    float4 erc[4];
    float4 vvc = vvn;
#pragma unroll
    for (int k = 0; k < 4; k++) exc[k] = exn[k];
#pragma unroll
    for (int r = 0; r < 4; r++) erc[r] = ern[r];
    if (hq < 63) {
      int o = hq * 4 + 4;
#pragma unroll
      for (int k = 0; k < 4; k++) exn[k] = pX[(size_t)(o + k) * CNX];
#pragma unroll
      for (int r = 0; r < 4; r++) ern[r] = *(const float4*)(pR + (size_t)r * CH + o);
      vvn = *(const float4*)(v_w + o);
    }
#pragma unroll
    for (int r = 0; r < 4; r++) {
      float4 er = erc[r];
      float a  = fmaf(er.x, exc[0], 1.0f);
      float bb = fmaf(er.y, exc[1], 1.0f);
      float c  = fmaf(er.z, exc[2], 1.0f);
      float d  = fmaf(er.w, exc[3], 1.0f);
      float q12 = a * bb, q34 = c * d;
      float p12 = fmaf(vvc.y, a, vvc.x * bb);
      float p34 = fmaf(vvc.w, c, vvc.z * d);
      float num = fmaf(p34, q12, p12 * q34);
      acc[r] = fmaf(num, fast_rcp(q12 * q34), acc[r]);
    }
  }
  const float NL2E = -2.0f * 1.4426950408889634f;
  float* pO = eT + ((size_t)b * CNR + r0) * CNX + x;
#pragma unroll
  for (int r = 0; r < 4; r++)
    pO[(size_t)r * CNX] = fast_exp2(acc[r] * NL2E);
}

// out[b][r][d] = sum_x eT[b][r][x]*X[b][x][d] / sum_x eT[b][r][x]
// Lanes = d (coalesced X); e[r][x] wave-uniform -> SGPR. Denominator via
// lane-parallel pre-pass + butterfly. X prefetched one step ahead.
// grid (CD/64=4, NR/16=32, B=8) = 1024 blocks (4/CU), 4 waves, 4 r/wave.
__global__ __launch_bounds__(256) void wsum_kernel(
    const float* __restrict__ eT, const float* __restrict__ X,
    float* __restrict__ out) {
  int b = blockIdx.z;
  int tid = threadIdx.x;
  int lane = tid & 63;
  int wv = __builtin_amdgcn_readfirstlane(tid >> 6);
  int d = blockIdx.x * 64 + lane;
  int r0 = blockIdx.y * 16 + wv * 4;
  const float* pE = eT + ((size_t)b * CNR + r0) * CNX;
  const float* pX = X + (size_t)b * CNX * CD + d;
  float inv[4];
#pragma unroll
  for (int r = 0; r < 4; r++) {
    const float4* row = (const float4*)(pE + (size_t)r * CNX);
    float4 ea = row[lane];
    float4 eb = row[lane + 64];
    float s = ((ea.x + ea.y) + (ea.z + ea.w)) + ((eb.x + eb.y) + (eb.z + eb.w));
#pragma unroll
    for (int off = 1; off < 64; off <<= 1) s += __shfl_xor(s, off, 64);
    inv[r] = fast_rcp(s);
  }
  float acc[4] = {};
  float xn[4];
#pragma unroll
  for (int k = 0; k < 4; k++) xn[k] = pX[(size_t)k * CD];
#pragma unroll 2
  for (int xq = 0; xq < 128; xq++) {
    float xc[4];
#pragma unroll
    for (int k = 0; k < 4; k++) xc[k] = xn[k];
    if (xq < 127) {
#pragma unroll
      for (int k = 0; k < 4; k++) xn[k] = pX[(size_t)(xq * 4 + 4 + k) * CD];
    }
#pragma unroll
    for (int r = 0; r < 4; r++) {
      float4 e4 = *(const float4*)(pE + (size_t)r * CNX + xq * 4);
      acc[r] = fmaf(e4.x, xc[0], acc[r]);
      acc[r] = fmaf(e4.y, xc[1], acc[r]);
      acc[r] = fmaf(e4.z, xc[2], acc[r]);
      acc[r] = fmaf(e4.w, xc[3], acc[r]);
    }
  }
  float* pO = out + ((size_t)b * CNR + r0) * CD + d;
#pragma unroll
  for (int r = 0; r < 4; r++)
    pO[(size_t)r * CD] = acc[r] * inv[r];
}

extern "C" void kernel_launch(void* const* d_in, const int* in_sizes, int n_in,
                              void* d_out, int out_size, void* d_ws, size_t ws_size,
                              hipStream_t stream) {
  const float* X     = (const float*)d_in[0];
  const float* ref   = (const float*)d_in[1];
  const float* W_X   = (const float*)d_in[2];
  const float* b_X   = (const float*)d_in[3];
  const float* W_ref = (const float*)d_in[4];
  const float* b_ref = (const float*)d_in[5];
  const float* v_w   = (const float*)d_in[6];
  float* out = (float*)d_out;
  float* ws  = (float*)d_ws;

  float* exT = ws;                       // [B][H][NX] = 1,048,576 floats
  float* erN = ws + 1048576;             // [B][NR][H] = 1,048,576 floats
  float* eT  = ws + 2097152;             // [B][NR][NX] = 2,097,152 floats

  proj_fused<<<dim3(128, 4, 2), 256, 0, stream>>>(X, ref, W_X, W_ref, b_X, b_ref, exT, erN);
  scores_kernel<<<dim3(8, 32, 8), 256, 0, stream>>>(exT, erN, v_w, eT);
  wsum_kernel<<<dim3(4, 32, 8), 256, 0, stream>>>(eT, X, out);
}